// Round 1
// baseline (791.380 us; speedup 1.0000x reference)
//
#include <hip/hip_runtime.h>
#include <stdint.h>

#define T_STEPS 512
#define BATCH   32
#define DIMN    1024
#define MROWS   (T_STEPS*BATCH)   // 16384

typedef _Float16 f16;
typedef _Float16 f16x8 __attribute__((ext_vector_type(8)));
typedef _Float16 f16x4 __attribute__((ext_vector_type(4)));
typedef float    f32x4 __attribute__((ext_vector_type(4)));

// ---------- async global -> LDS, 16 B per lane ----------
__device__ __forceinline__ void load16_to_lds(const f16* gptr, f16* lptr) {
  __builtin_amdgcn_global_load_lds(
      (const __attribute__((address_space(1))) unsigned int*)(uintptr_t)gptr,
      (__attribute__((address_space(3))) unsigned int*)(uint32_t)(uintptr_t)lptr,
      16, 0, 0);
}

// ---------- f32 -> f16 convert, 8 elems/thread ----------
__global__ __launch_bounds__(256) void cvt_f32_f16(const float* __restrict__ src,
                                                   f16* __restrict__ dst, int n8) {
  int i = blockIdx.x * 256 + threadIdx.x;
  if (i >= n8) return;
  const float4* s = (const float4*)src;
  float4 a = s[2*i], b = s[2*i + 1];
  f16x8 o = { (f16)a.x, (f16)a.y, (f16)a.z, (f16)a.w,
              (f16)b.x, (f16)b.y, (f16)b.z, (f16)b.w };
  *(f16x8*)(dst + (size_t)i * 8) = o;
}

// ---------- 128x128-tile fp16 MFMA GEMM:  C[m,n] = sum_k A[m,k]*B[n,k] (+bias[n]) ----------
// A: [M,K] row-major fp16, B: [N,K] row-major fp16, K=N=1024 fixed, M=16384.
// LDS chunk swizzle: row r, stored 16B-chunk c holds data chunk c ^ ((r>>1)&3)
// -> conflict-free ds_read_b128 fragment reads.
__global__ __launch_bounds__(256) void gemm_bt_f16(
    const f16* __restrict__ A, const f16* __restrict__ B,
    const float* __restrict__ bias, f16* __restrict__ Cout) {
  constexpr int K = DIMN;
  constexpr int N = DIMN;
  __shared__ f16 Alds[128 * 32];
  __shared__ f16 Blds[128 * 32];
  const int tid  = threadIdx.x;
  const int lane = tid & 63;
  const int wid  = tid >> 6;
  const int wm = wid & 1, wn = wid >> 1;       // 2x2 waves -> 64x64 each
  const int l15  = lane & 15;
  const int quad = lane >> 4;
  const int swz  = (l15 >> 1) & 3;
  const int rowBase = blockIdx.x * 128;        // M
  const int colBase = blockIdx.y * 128;        // N
  const int sr = lane >> 2;                    // staging row within 16-row group
  const int cs = lane & 3;                     // stored chunk index

  f32x4 acc[4][4] = {};

  for (int k0 = 0; k0 < K; k0 += 32) {
    #pragma unroll
    for (int i = 0; i < 2; ++i) {
      const int g = wid + i * 4;               // 8 groups of 16 rows
      const int r = g * 16 + sr;
      const int cd = cs ^ ((r >> 1) & 3);      // data chunk this lane fetches
      load16_to_lds(A + (size_t)(rowBase + r) * K + k0 + cd * 8, Alds + g * 512);
      load16_to_lds(B + (size_t)(colBase + r) * K + k0 + cd * 8, Blds + g * 512);
    }
    __syncthreads();
    f16x8 af[4], bf[4];
    #pragma unroll
    for (int mi = 0; mi < 4; ++mi) {
      const int r = wm * 64 + mi * 16 + l15;
      af[mi] = *(const f16x8*)(Alds + r * 32 + (quad ^ swz) * 8);
    }
    #pragma unroll
    for (int ni = 0; ni < 4; ++ni) {
      const int r = wn * 64 + ni * 16 + l15;
      bf[ni] = *(const f16x8*)(Blds + r * 32 + (quad ^ swz) * 8);
    }
    #pragma unroll
    for (int mi = 0; mi < 4; ++mi)
      #pragma unroll
      for (int ni = 0; ni < 4; ++ni)
        acc[mi][ni] = __builtin_amdgcn_mfma_f32_16x16x32_f16(af[mi], bf[ni], acc[mi][ni], 0, 0, 0);
    __syncthreads();
  }

  // epilogue: D row = quad*4 + j, col = l15 (verified C/D layout)
  #pragma unroll
  for (int ni = 0; ni < 4; ++ni) {
    const int n = colBase + wn * 64 + ni * 16 + l15;
    const float bv = bias ? bias[n] : 0.0f;
    #pragma unroll
    for (int mi = 0; mi < 4; ++mi) {
      const int m0 = rowBase + wm * 64 + mi * 16 + quad * 4;
      #pragma unroll
      for (int j = 0; j < 4; ++j)
        Cout[(size_t)(m0 + j) * N + n] = (f16)(acc[mi][ni][j] + bv);
    }
  }
}

// ---------- pass-0 scan: h_{t+1} = rmsnorm(h_t + alpha*wx_t), store h_t (t=0..511) as fp16 ----------
__global__ __launch_bounds__(256) void scan0_kernel(
    const f16* __restrict__ Wx,        // [T,B,D] (bias already added)
    const float* __restrict__ h0,      // [B,D]
    const float* __restrict__ log_alpha,
    f16* __restrict__ G) {             // [T,B,D]: G[t] = h_t
  const int b = blockIdx.x;
  const int tid = threadIdx.x;
  const int lane = tid & 63, wid = tid >> 6;
  __shared__ float red[2][4];
  const float alpha = expf(log_alpha[0]);
  const size_t rowoff = (size_t)b * DIMN + tid * 4;
  float4 h = *(const float4*)(h0 + rowoff);
  { f16x4 g = {(f16)h.x, (f16)h.y, (f16)h.z, (f16)h.w};
    *(f16x4*)(G + rowoff) = g; }                         // G[0] = h0
  f16x4 wxv = *(const f16x4*)(Wx + rowoff);              // t = 0
  for (int t = 0; t < T_STEPS - 1; ++t) {
    const int tn = (t + 1 < T_STEPS - 1) ? t + 1 : t;    // prefetch next step
    f16x4 wxn = *(const f16x4*)(Wx + (size_t)tn * BATCH * DIMN + rowoff);
    h.x += alpha * (float)wxv[0];
    h.y += alpha * (float)wxv[1];
    h.z += alpha * (float)wxv[2];
    h.w += alpha * (float)wxv[3];
    float s = h.x*h.x + h.y*h.y + h.z*h.z + h.w*h.w;
    #pragma unroll
    for (int off = 1; off < 64; off <<= 1) s += __shfl_xor(s, off);
    if (lane == 0) red[t & 1][wid] = s;
    __syncthreads();
    s = red[t & 1][0] + red[t & 1][1] + red[t & 1][2] + red[t & 1][3];
    const float r = rsqrtf(s * (1.0f / DIMN) + 1e-6f);
    h.x *= r; h.y *= r; h.z *= r; h.w *= r;
    f16x4 g = {(f16)h.x, (f16)h.y, (f16)h.z, (f16)h.w};
    *(f16x4*)(G + (size_t)(t + 1) * BATCH * DIMN + rowoff) = g;
    wxv = wxn;
  }
}

// ---------- pass-1 scan with corrections: h_{t+1} = rmsnorm(h_t + alpha*wx_t + beta*C_t) ----------
__global__ __launch_bounds__(256) void scan1_kernel(
    const f16* __restrict__ Wx, const f16* __restrict__ C,
    const float* __restrict__ h0,
    const float* __restrict__ log_alpha, const float* __restrict__ log_beta,
    float* __restrict__ outs,          // [T,B,D]
    float* __restrict__ hout) {        // [T+1,B,D]
  const int b = blockIdx.x;
  const int tid = threadIdx.x;
  const int lane = tid & 63, wid = tid >> 6;
  __shared__ float red[2][4];
  const float alpha = expf(log_alpha[0]);
  const float beta  = 0.1f / (1.0f + expf(-log_beta[0]));
  const size_t rowoff = (size_t)b * DIMN + tid * 4;
  float4 h = *(const float4*)(h0 + rowoff);
  *(float4*)(hout + rowoff) = h;                         // h[0] = h0
  f16x4 wxv = *(const f16x4*)(Wx + rowoff);
  f16x4 cv  = *(const f16x4*)(C + rowoff);
  for (int t = 0; t < T_STEPS; ++t) {
    const int tn = (t + 1 < T_STEPS) ? t + 1 : t;
    f16x4 wxn = *(const f16x4*)(Wx + (size_t)tn * BATCH * DIMN + rowoff);
    f16x4 cn  = *(const f16x4*)(C  + (size_t)tn * BATCH * DIMN + rowoff);
    h.x += alpha * (float)wxv[0] + beta * (float)cv[0];
    h.y += alpha * (float)wxv[1] + beta * (float)cv[1];
    h.z += alpha * (float)wxv[2] + beta * (float)cv[2];
    h.w += alpha * (float)wxv[3] + beta * (float)cv[3];
    float s = h.x*h.x + h.y*h.y + h.z*h.z + h.w*h.w;
    #pragma unroll
    for (int off = 1; off < 64; off <<= 1) s += __shfl_xor(s, off);
    if (lane == 0) red[t & 1][wid] = s;
    __syncthreads();
    s = red[t & 1][0] + red[t & 1][1] + red[t & 1][2] + red[t & 1][3];
    const float r = rsqrtf(s * (1.0f / DIMN) + 1e-6f);
    h.x *= r; h.y *= r; h.z *= r; h.w *= r;
    *(float4*)(hout + (size_t)(t + 1) * BATCH * DIMN + rowoff) = h;
    float4 o;
    o.x = h.x * h.x / (1.0f + expf(-h.x));
    o.y = h.y * h.y / (1.0f + expf(-h.y));
    o.z = h.z * h.z / (1.0f + expf(-h.z));
    o.w = h.w * h.w / (1.0f + expf(-h.w));
    *(float4*)(outs + (size_t)t * BATCH * DIMN + rowoff) = o;
    wxv = wxn; cv = cn;
  }
}

extern "C" void kernel_launch(void* const* d_in, const int* in_sizes, int n_in,
                              void* d_out, int out_size, void* d_ws, size_t ws_size,
                              hipStream_t stream) {
  const float* x    = (const float*)d_in[0];   // [512,32,1024]
  const float* h0   = (const float*)d_in[1];   // [32,1024]
  const float* W    = (const float*)d_in[2];   // [1024,1024]
  const float* Wh   = (const float*)d_in[3];   // [1024,1024]
  const float* bias = (const float*)d_in[4];   // [1024]
  const float* la   = (const float*)d_in[5];
  const float* lb   = (const float*)d_in[6];

  // workspace layout (bytes): xh 32M | W16 2M | Wh16 2M | Wx16 32M | G16 32M | C16 32M = 132 MB
  char* ws = (char*)d_ws;
  f16* XH   = (f16*)(ws);
  f16* W16  = (f16*)(ws + 33554432ull);
  f16* WH16 = (f16*)(ws + 35651584ull);
  f16* WX16 = (f16*)(ws + 37748736ull);
  f16* G16  = (f16*)(ws + 71303168ull);
  f16* C16  = (f16*)(ws + 104857600ull);

  float* outs = (float*)d_out;                               // [512,32,1024]
  float* hout = outs + (size_t)T_STEPS * BATCH * DIMN;       // [513,32,1024]

  cvt_f32_f16<<<dim3((MROWS * DIMN / 8) / 256), 256, 0, stream>>>(x, XH, MROWS * DIMN / 8);
  cvt_f32_f16<<<dim3((DIMN * DIMN / 8) / 256), 256, 0, stream>>>(W, W16, DIMN * DIMN / 8);
  cvt_f32_f16<<<dim3((DIMN * DIMN / 8) / 256), 256, 0, stream>>>(Wh, WH16, DIMN * DIMN / 8);

  // Wx = x @ W^T + b   (fp16 in, fp32 acc, fp16 out)
  gemm_bt_f16<<<dim3(MROWS / 128, DIMN / 128), 256, 0, stream>>>(XH, W16, bias, WX16);

  // pass-0 scan (no W_h term), stores h_0..h_511 as fp16
  scan0_kernel<<<dim3(BATCH), 256, 0, stream>>>(WX16, h0, la, G16);

  // corrections C_t = h0pass_t @ W_h^T  (beta applied in scan-1)
  gemm_bt_f16<<<dim3(MROWS / 128, DIMN / 128), 256, 0, stream>>>(G16, WH16, nullptr, C16);

  // pass-1 scan with corrections, writes both outputs
  scan1_kernel<<<dim3(BATCH), 256, 0, stream>>>(WX16, C16, h0, la, lb, outs, hout);
}

// Round 2
// 645.904 us; speedup vs baseline: 1.2252x; 1.2252x over previous
//
#include <hip/hip_runtime.h>
#include <stdint.h>

#define T_STEPS 512
#define BATCH   32
#define DIMN    1024
#define MROWS   (T_STEPS*BATCH)   // 16384
#define BD      (BATCH*DIMN)      // 32768

typedef _Float16 f16;
typedef _Float16 f16x8 __attribute__((ext_vector_type(8)));
typedef _Float16 f16x4 __attribute__((ext_vector_type(4)));
typedef float    f32x4 __attribute__((ext_vector_type(4)));

// ---------- async global -> LDS, 16 B per lane ----------
__device__ __forceinline__ void load16_to_lds(const f16* gptr, f16* lptr) {
  __builtin_amdgcn_global_load_lds(
      (const __attribute__((address_space(1))) unsigned int*)(uintptr_t)gptr,
      (__attribute__((address_space(3))) unsigned int*)(uint32_t)(uintptr_t)lptr,
      16, 0, 0);
}

// ---------- DPP row-rotate add (rotation within 16-lane rows; direction-agnostic for reduction) ----------
template<int CTRL>
__device__ __forceinline__ float dpp_ror_add(float v) {
  int iv = __float_as_int(v);
  int rv = __builtin_amdgcn_update_dpp(iv, iv, CTRL, 0xF, 0xF, false);
  return v + __int_as_float(rv);
}

__device__ __forceinline__ float wave_sum64(float s) {
  s = dpp_ror_add<0x128>(s);   // row_ror:8
  s = dpp_ror_add<0x124>(s);   // row_ror:4
  s = dpp_ror_add<0x122>(s);   // row_ror:2
  s = dpp_ror_add<0x121>(s);   // row_ror:1  -> every lane has its row-of-16 sum
  s += __shfl_xor(s, 16);
  s += __shfl_xor(s, 32);
  return s;
}

// ---------- f32 -> f16 convert, 8 elems/thread ----------
__global__ __launch_bounds__(256) void cvt_f32_f16(const float* __restrict__ src,
                                                   f16* __restrict__ dst, int n8) {
  int i = blockIdx.x * 256 + threadIdx.x;
  if (i >= n8) return;
  const float4* s = (const float4*)src;
  float4 a = s[2*i], b = s[2*i + 1];
  f16x8 o = { (f16)a.x, (f16)a.y, (f16)a.z, (f16)a.w,
              (f16)b.x, (f16)b.y, (f16)b.z, (f16)b.w };
  *(f16x8*)(dst + (size_t)i * 8) = o;
}

// ---------- 128x128-tile fp16 MFMA GEMM:  C[m,n] = sum_k A[m,k]*B[n,k] (+bias[n]) ----------
__global__ __launch_bounds__(256) void gemm_bt_f16(
    const f16* __restrict__ A, const f16* __restrict__ B,
    const float* __restrict__ bias, f16* __restrict__ Cout) {
  constexpr int K = DIMN;
  constexpr int N = DIMN;
  __shared__ f16 Alds[128 * 32];
  __shared__ f16 Blds[128 * 32];
  const int tid  = threadIdx.x;
  const int lane = tid & 63;
  const int wid  = tid >> 6;
  const int wm = wid & 1, wn = wid >> 1;       // 2x2 waves -> 64x64 each
  const int l15  = lane & 15;
  const int quad = lane >> 4;
  const int swz  = (l15 >> 1) & 3;
  const int rowBase = blockIdx.x * 128;        // M
  const int colBase = blockIdx.y * 128;        // N
  const int sr = lane >> 2;                    // staging row within 16-row group
  const int cs = lane & 3;                     // stored chunk index

  f32x4 acc[4][4] = {};

  for (int k0 = 0; k0 < K; k0 += 32) {
    #pragma unroll
    for (int i = 0; i < 2; ++i) {
      const int g = wid + i * 4;               // 8 groups of 16 rows
      const int r = g * 16 + sr;
      const int cd = cs ^ ((r >> 1) & 3);      // data chunk this lane fetches
      load16_to_lds(A + (size_t)(rowBase + r) * K + k0 + cd * 8, Alds + g * 512);
      load16_to_lds(B + (size_t)(colBase + r) * K + k0 + cd * 8, Blds + g * 512);
    }
    __syncthreads();
    f16x8 af[4], bf[4];
    #pragma unroll
    for (int mi = 0; mi < 4; ++mi) {
      const int r = wm * 64 + mi * 16 + l15;
      af[mi] = *(const f16x8*)(Alds + r * 32 + (quad ^ swz) * 8);
    }
    #pragma unroll
    for (int ni = 0; ni < 4; ++ni) {
      const int r = wn * 64 + ni * 16 + l15;
      bf[ni] = *(const f16x8*)(Blds + r * 32 + (quad ^ swz) * 8);
    }
    #pragma unroll
    for (int mi = 0; mi < 4; ++mi)
      #pragma unroll
      for (int ni = 0; ni < 4; ++ni)
        acc[mi][ni] = __builtin_amdgcn_mfma_f32_16x16x32_f16(af[mi], bf[ni], acc[mi][ni], 0, 0, 0);
    __syncthreads();
  }

  #pragma unroll
  for (int ni = 0; ni < 4; ++ni) {
    const int n = colBase + wn * 64 + ni * 16 + l15;
    const float bv = bias ? bias[n] : 0.0f;
    #pragma unroll
    for (int mi = 0; mi < 4; ++mi) {
      const int m0 = rowBase + wm * 64 + mi * 16 + quad * 4;
      #pragma unroll
      for (int j = 0; j < 4; ++j)
        Cout[(size_t)(m0 + j) * N + n] = (f16)(acc[mi][ni][j] + bv);
    }
  }
}

// ---------- pass-0 scan (no W_h term): one WAVE per batch row, depth-8 register prefetch ----------
// lane l owns elems [l*8, l*8+8) and [512+l*8, 512+l*8+8).
__global__ __launch_bounds__(64) void scan0_wave(
    const f16* __restrict__ Wx,        // [T,B,D] (bias already added)
    const float* __restrict__ h0,      // [B,D]
    const float* __restrict__ log_alpha,
    f16* __restrict__ G0) {            // [T,B,D]: G0[t] = h_t
  const int b = blockIdx.x;
  const int l = threadIdx.x;
  const float alpha = expf(log_alpha[0]);
  const size_t base = (size_t)b * DIMN + (size_t)l * 8;

  float h[16];
  {
    float4 a0 = *(const float4*)(h0 + base);
    float4 a1 = *(const float4*)(h0 + base + 4);
    float4 a2 = *(const float4*)(h0 + base + 512);
    float4 a3 = *(const float4*)(h0 + base + 516);
    h[0]=a0.x; h[1]=a0.y; h[2]=a0.z; h[3]=a0.w;
    h[4]=a1.x; h[5]=a1.y; h[6]=a1.z; h[7]=a1.w;
    h[8]=a2.x; h[9]=a2.y; h[10]=a2.z; h[11]=a2.w;
    h[12]=a3.x; h[13]=a3.y; h[14]=a3.z; h[15]=a3.w;
    f16x8 g0, g1;
    #pragma unroll
    for (int i = 0; i < 8; ++i) { g0[i] = (f16)h[i]; g1[i] = (f16)h[i+8]; }
    *(f16x8*)(G0 + base) = g0;                 // G0[0] = h0
    *(f16x8*)(G0 + base + 512) = g1;
  }

  f16x8 bw0[8], bw1[8];
  #pragma unroll
  for (int j = 0; j < 8; ++j) {
    bw0[j] = *(const f16x8*)(Wx + (size_t)j * BD + base);
    bw1[j] = *(const f16x8*)(Wx + (size_t)j * BD + base + 512);
  }

  for (int tb = 0; tb < T_STEPS; tb += 8) {
    #pragma unroll
    for (int j = 0; j < 8; ++j) {
      const int t = tb + j;
      f16x8 w0 = bw0[j], w1 = bw1[j];
      int tn = t + 8; if (tn > T_STEPS - 1) tn = T_STEPS - 1;
      bw0[j] = *(const f16x8*)(Wx + (size_t)tn * BD + base);
      bw1[j] = *(const f16x8*)(Wx + (size_t)tn * BD + base + 512);
      #pragma unroll
      for (int i = 0; i < 8; ++i) {
        h[i]   = fmaf(alpha, (float)w0[i], h[i]);
        h[i+8] = fmaf(alpha, (float)w1[i], h[i+8]);
      }
      float p[8];
      #pragma unroll
      for (int i = 0; i < 8; ++i) p[i] = h[2*i]*h[2*i] + h[2*i+1]*h[2*i+1];
      float s = ((p[0]+p[1])+(p[2]+p[3])) + ((p[4]+p[5])+(p[6]+p[7]));
      s = wave_sum64(s);
      const float r = rsqrtf(s * (1.0f / DIMN) + 1e-6f);
      #pragma unroll
      for (int i = 0; i < 16; ++i) h[i] *= r;
      if (t < T_STEPS - 1) {
        f16x8 g0, g1;
        #pragma unroll
        for (int i = 0; i < 8; ++i) { g0[i] = (f16)h[i]; g1[i] = (f16)h[i+8]; }
        *(f16x8*)(G0 + (size_t)(t+1) * BD + base) = g0;
        *(f16x8*)(G0 + (size_t)(t+1) * BD + base + 512) = g1;
      }
    }
  }
}

// ---------- pass-1 scan with corrections: stores G1[t] = h_{t+1} as fp16 only ----------
__global__ __launch_bounds__(64) void scan1_wave(
    const f16* __restrict__ Wx, const f16* __restrict__ C,
    const float* __restrict__ h0,
    const float* __restrict__ log_alpha, const float* __restrict__ log_beta,
    f16* __restrict__ G1) {            // [T,B,D]: G1[t] = h_{t+1}
  const int b = blockIdx.x;
  const int l = threadIdx.x;
  const float alpha = expf(log_alpha[0]);
  const float beta  = 0.1f / (1.0f + expf(-log_beta[0]));
  const size_t base = (size_t)b * DIMN + (size_t)l * 8;

  float h[16];
  {
    float4 a0 = *(const float4*)(h0 + base);
    float4 a1 = *(const float4*)(h0 + base + 4);
    float4 a2 = *(const float4*)(h0 + base + 512);
    float4 a3 = *(const float4*)(h0 + base + 516);
    h[0]=a0.x; h[1]=a0.y; h[2]=a0.z; h[3]=a0.w;
    h[4]=a1.x; h[5]=a1.y; h[6]=a1.z; h[7]=a1.w;
    h[8]=a2.x; h[9]=a2.y; h[10]=a2.z; h[11]=a2.w;
    h[12]=a3.x; h[13]=a3.y; h[14]=a3.z; h[15]=a3.w;
  }

  f16x8 bw0[8], bw1[8], bc0[8], bc1[8];
  #pragma unroll
  for (int j = 0; j < 8; ++j) {
    bw0[j] = *(const f16x8*)(Wx + (size_t)j * BD + base);
    bw1[j] = *(const f16x8*)(Wx + (size_t)j * BD + base + 512);
    bc0[j] = *(const f16x8*)(C  + (size_t)j * BD + base);
    bc1[j] = *(const f16x8*)(C  + (size_t)j * BD + base + 512);
  }

  for (int tb = 0; tb < T_STEPS; tb += 8) {
    #pragma unroll
    for (int j = 0; j < 8; ++j) {
      const int t = tb + j;
      f16x8 w0 = bw0[j], w1 = bw1[j], c0 = bc0[j], c1 = bc1[j];
      int tn = t + 8; if (tn > T_STEPS - 1) tn = T_STEPS - 1;
      bw0[j] = *(const f16x8*)(Wx + (size_t)tn * BD + base);
      bw1[j] = *(const f16x8*)(Wx + (size_t)tn * BD + base + 512);
      bc0[j] = *(const f16x8*)(C  + (size_t)tn * BD + base);
      bc1[j] = *(const f16x8*)(C  + (size_t)tn * BD + base + 512);
      #pragma unroll
      for (int i = 0; i < 8; ++i) {
        h[i]   += alpha * (float)w0[i] + beta * (float)c0[i];
        h[i+8] += alpha * (float)w1[i] + beta * (float)c1[i];
      }
      float p[8];
      #pragma unroll
      for (int i = 0; i < 8; ++i) p[i] = h[2*i]*h[2*i] + h[2*i+1]*h[2*i+1];
      float s = ((p[0]+p[1])+(p[2]+p[3])) + ((p[4]+p[5])+(p[6]+p[7]));
      s = wave_sum64(s);
      const float r = rsqrtf(s * (1.0f / DIMN) + 1e-6f);
      #pragma unroll
      for (int i = 0; i < 16; ++i) h[i] *= r;
      f16x8 g0, g1;
      #pragma unroll
      for (int i = 0; i < 8; ++i) { g0[i] = (f16)h[i]; g1[i] = (f16)h[i+8]; }
      *(f16x8*)(G1 + (size_t)t * BD + base) = g0;
      *(f16x8*)(G1 + (size_t)t * BD + base + 512) = g1;
    }
  }
}

// ---------- expand: outs[t] = g*g*sigmoid(g), hout[t+1] = g (g = G1[t]); hout[0] = h0 ----------
__global__ __launch_bounds__(256) void expand_kernel(
    const f16* __restrict__ G1, const float* __restrict__ h0,
    float* __restrict__ outs, float* __restrict__ hout) {
  const long long total8 = (long long)T_STEPS * BD / 8;   // 2,097,152
  const long long idx = (long long)blockIdx.x * 256 + threadIdx.x;
  if (idx < total8) {
    const size_t e = (size_t)idx * 8;
    f16x8 g = *(const f16x8*)(G1 + e);
    float v[8], o[8];
    #pragma unroll
    for (int i = 0; i < 8; ++i) v[i] = (float)g[i];
    #pragma unroll
    for (int i = 0; i < 8; ++i) o[i] = v[i] * v[i] / (1.0f + expf(-v[i]));
    *(float4*)(hout + BD + e)     = make_float4(v[0], v[1], v[2], v[3]);
    *(float4*)(hout + BD + e + 4) = make_float4(v[4], v[5], v[6], v[7]);
    *(float4*)(outs + e)     = make_float4(o[0], o[1], o[2], o[3]);
    *(float4*)(outs + e + 4) = make_float4(o[4], o[5], o[6], o[7]);
  } else {
    const size_t j = (size_t)(idx - total8) * 8;
    if (j < (size_t)BD) {
      float4 a0 = *(const float4*)(h0 + j);
      float4 a1 = *(const float4*)(h0 + j + 4);
      *(float4*)(hout + j)     = a0;
      *(float4*)(hout + j + 4) = a1;
    }
  }
}

extern "C" void kernel_launch(void* const* d_in, const int* in_sizes, int n_in,
                              void* d_out, int out_size, void* d_ws, size_t ws_size,
                              hipStream_t stream) {
  const float* x    = (const float*)d_in[0];   // [512,32,1024]
  const float* h0   = (const float*)d_in[1];   // [32,1024]
  const float* W    = (const float*)d_in[2];   // [1024,1024]
  const float* Wh   = (const float*)d_in[3];   // [1024,1024]
  const float* bias = (const float*)d_in[4];   // [1024]
  const float* la   = (const float*)d_in[5];
  const float* lb   = (const float*)d_in[6];

  // workspace layout (bytes), total 132 MB (same as round 1):
  // [0,32M):    XH (x in fp16) -- later reused as G1 (free after GEMM1)
  // [32M,34M):  W16
  // [34M,36M):  WH16
  // [36M,68M):  WX16
  // [68M,100M): G0
  // [100M,132M):C16
  char* ws = (char*)d_ws;
  f16* XH   = (f16*)(ws);
  f16* W16  = (f16*)(ws + 33554432ull);
  f16* WH16 = (f16*)(ws + 35651584ull);
  f16* WX16 = (f16*)(ws + 37748736ull);
  f16* G0   = (f16*)(ws + 71303168ull);
  f16* C16  = (f16*)(ws + 104857600ull);
  f16* G1   = XH;                               // alias: XH dead after GEMM1

  float* outs = (float*)d_out;                               // [512,32,1024]
  float* hout = outs + (size_t)T_STEPS * BD;                 // [513,32,1024]

  cvt_f32_f16<<<dim3((MROWS * DIMN / 8) / 256), 256, 0, stream>>>(x, XH, MROWS * DIMN / 8);
  cvt_f32_f16<<<dim3((DIMN * DIMN / 8) / 256), 256, 0, stream>>>(W, W16, DIMN * DIMN / 8);
  cvt_f32_f16<<<dim3((DIMN * DIMN / 8) / 256), 256, 0, stream>>>(Wh, WH16, DIMN * DIMN / 8);

  // Wx = x @ W^T + b
  gemm_bt_f16<<<dim3(MROWS / 128, DIMN / 128), 256, 0, stream>>>(XH, W16, bias, WX16);

  // pass-0 scan (no W_h term): G0[t] = h_t
  scan0_wave<<<dim3(BATCH), 64, 0, stream>>>(WX16, h0, la, G0);

  // corrections C_t = h0pass_t @ W_h^T
  gemm_bt_f16<<<dim3(MROWS / 128, DIMN / 128), 256, 0, stream>>>(G0, WH16, nullptr, C16);

  // pass-1 scan with corrections: G1[t] = h_{t+1} (fp16)
  scan1_wave<<<dim3(BATCH), 64, 0, stream>>>(WX16, C16, h0, la, lb, G1);

  // expand to fp32 outputs at full-device BW
  const int total8 = T_STEPS * BD / 8;
  expand_kernel<<<dim3(total8 / 256 + 16), 256, 0, stream>>>(G1, h0, outs, hout);
}

// Round 4
// 555.038 us; speedup vs baseline: 1.4258x; 1.1637x over previous
//
#include <hip/hip_runtime.h>
#include <stdint.h>

#define T_STEPS 512
#define BATCH   32
#define DIMN    1024
#define MROWS   (T_STEPS*BATCH)   // 16384
#define BD      (BATCH*DIMN)      // 32768

typedef _Float16 f16;
typedef _Float16 f16x8 __attribute__((ext_vector_type(8)));
typedef _Float16 f16x4 __attribute__((ext_vector_type(4)));
typedef _Float16 f16x2 __attribute__((ext_vector_type(2)));
typedef float    f32x4 __attribute__((ext_vector_type(4)));

union U8 { f16x8 v; f16x2 p[4]; };

// packed f32x2 -> f16x2 (RTZ), bit-cast to our _Float16 vector type
__device__ __forceinline__ f16x2 pkrtz(float a, float b) {
  return __builtin_bit_cast(f16x2, __builtin_amdgcn_cvt_pkrtz(a, b));
}

// ---------- async global -> LDS, 16 B per lane ----------
__device__ __forceinline__ void load16_to_lds(const f16* gptr, f16* lptr) {
  __builtin_amdgcn_global_load_lds(
      (const __attribute__((address_space(1))) unsigned int*)(uintptr_t)gptr,
      (__attribute__((address_space(3))) unsigned int*)(uint32_t)(uintptr_t)lptr,
      16, 0, 0);
}

// ---------- DPP row-rotate add ----------
template<int CTRL>
__device__ __forceinline__ float dpp_ror_add(float v) {
  int iv = __float_as_int(v);
  int rv = __builtin_amdgcn_update_dpp(iv, iv, CTRL, 0xF, 0xF, false);
  return v + __int_as_float(rv);
}

// all-lanes sum of 64 lanes: 4 DPP row-ror adds (row sums) + readlane x4 + 3 adds.
__device__ __forceinline__ float wave_allsum(float s) {
  s = dpp_ror_add<0x128>(s);   // row_ror:8
  s = dpp_ror_add<0x124>(s);   // row_ror:4
  s = dpp_ror_add<0x122>(s);   // row_ror:2
  s = dpp_ror_add<0x121>(s);   // row_ror:1 -> each lane: sum of its 16-lane row
  float a = __int_as_float(__builtin_amdgcn_readlane(__float_as_int(s), 0));
  float b = __int_as_float(__builtin_amdgcn_readlane(__float_as_int(s), 16));
  float c = __int_as_float(__builtin_amdgcn_readlane(__float_as_int(s), 32));
  float d = __int_as_float(__builtin_amdgcn_readlane(__float_as_int(s), 48));
  return (a + b) + (c + d);
}

// ---------- f32 -> f16 convert, 8 elems/thread ----------
__global__ __launch_bounds__(256) void cvt_f32_f16(const float* __restrict__ src,
                                                   f16* __restrict__ dst, int n8) {
  int i = blockIdx.x * 256 + threadIdx.x;
  if (i >= n8) return;
  const float4* s = (const float4*)src;
  float4 a = s[2*i], b = s[2*i + 1];
  f16x8 o = { (f16)a.x, (f16)a.y, (f16)a.z, (f16)a.w,
              (f16)b.x, (f16)b.y, (f16)b.z, (f16)b.w };
  *(f16x8*)(dst + (size_t)i * 8) = o;
}

// ---------- 128x128-tile fp16 MFMA GEMM:  C[m,n] = scale*(sum_k A[m,k]*B[n,k] + bias[n]) ----------
// mode 0: scale = exp(la[0]), with bias.  mode 1: scale = 64 * 0.1*sigmoid(lb[0]), no bias.
__global__ __launch_bounds__(256) void gemm_bt_f16(
    const f16* __restrict__ A, const f16* __restrict__ B,
    const float* __restrict__ bias, f16* __restrict__ Cout,
    const float* __restrict__ la, const float* __restrict__ lb, int mode) {
  constexpr int K = DIMN;
  constexpr int N = DIMN;
  __shared__ f16 Alds[128 * 32];
  __shared__ f16 Blds[128 * 32];
  const int tid  = threadIdx.x;
  const int lane = tid & 63;
  const int wid  = tid >> 6;
  const int wm = wid & 1, wn = wid >> 1;       // 2x2 waves -> 64x64 each
  const int l15  = lane & 15;
  const int quad = lane >> 4;
  const int swz  = (l15 >> 1) & 3;
  const int rowBase = blockIdx.x * 128;        // M
  const int colBase = blockIdx.y * 128;        // N
  const int sr = lane >> 2;
  const int cs = lane & 3;

  const float scale = (mode == 0) ? expf(la[0])
                                  : 64.0f * 0.1f / (1.0f + expf(-lb[0]));

  f32x4 acc[4][4] = {};

  for (int k0 = 0; k0 < K; k0 += 32) {
    #pragma unroll
    for (int i = 0; i < 2; ++i) {
      const int g = wid + i * 4;
      const int r = g * 16 + sr;
      const int cd = cs ^ ((r >> 1) & 3);
      load16_to_lds(A + (size_t)(rowBase + r) * K + k0 + cd * 8, Alds + g * 512);
      load16_to_lds(B + (size_t)(colBase + r) * K + k0 + cd * 8, Blds + g * 512);
    }
    __syncthreads();
    f16x8 af[4], bf[4];
    #pragma unroll
    for (int mi = 0; mi < 4; ++mi) {
      const int r = wm * 64 + mi * 16 + l15;
      af[mi] = *(const f16x8*)(Alds + r * 32 + (quad ^ swz) * 8);
    }
    #pragma unroll
    for (int ni = 0; ni < 4; ++ni) {
      const int r = wn * 64 + ni * 16 + l15;
      bf[ni] = *(const f16x8*)(Blds + r * 32 + (quad ^ swz) * 8);
    }
    #pragma unroll
    for (int mi = 0; mi < 4; ++mi)
      #pragma unroll
      for (int ni = 0; ni < 4; ++ni)
        acc[mi][ni] = __builtin_amdgcn_mfma_f32_16x16x32_f16(af[mi], bf[ni], acc[mi][ni], 0, 0, 0);
    __syncthreads();
  }

  #pragma unroll
  for (int ni = 0; ni < 4; ++ni) {
    const int n = colBase + wn * 64 + ni * 16 + l15;
    const float bv = (mode == 0) ? bias[n] : 0.0f;
    #pragma unroll
    for (int mi = 0; mi < 4; ++mi) {
      const int m0 = rowBase + wm * 64 + mi * 16 + quad * 4;
      #pragma unroll
      for (int j = 0; j < 4; ++j)
        Cout[(size_t)(m0 + j) * N + n] = (f16)(scale * (acc[mi][ni][j] + bv));
    }
  }
}

// ---------- pass-0 scan: h_{t+1} = rmsnorm(h_t + w_t), w pre-scaled by alpha ----------
__global__ __launch_bounds__(64) void scan0_wave(
    const f16* __restrict__ Wx,        // [T,B,D] = alpha*(xW^T + b), fp16
    const float* __restrict__ h0,
    f16* __restrict__ G0) {            // [T,B,D]: G0[t] = h_t
  const int b = blockIdx.x;
  const int l = threadIdx.x;
  const size_t base = (size_t)b * DIMN + (size_t)l * 8;

  float h[16];
  {
    float4 a0 = *(const float4*)(h0 + base);
    float4 a1 = *(const float4*)(h0 + base + 4);
    float4 a2 = *(const float4*)(h0 + base + 512);
    float4 a3 = *(const float4*)(h0 + base + 516);
    h[0]=a0.x; h[1]=a0.y; h[2]=a0.z; h[3]=a0.w;
    h[4]=a1.x; h[5]=a1.y; h[6]=a1.z; h[7]=a1.w;
    h[8]=a2.x; h[9]=a2.y; h[10]=a2.z; h[11]=a2.w;
    h[12]=a3.x; h[13]=a3.y; h[14]=a3.z; h[15]=a3.w;
    f16x8 g0, g1;
    #pragma unroll
    for (int i = 0; i < 8; ++i) { g0[i] = (f16)h[i]; g1[i] = (f16)h[i+8]; }
    *(f16x8*)(G0 + base) = g0;
    *(f16x8*)(G0 + base + 512) = g1;
  }

  U8 bw0[8], bw1[8];
  #pragma unroll
  for (int j = 0; j < 8; ++j) {
    bw0[j].v = *(const f16x8*)(Wx + (size_t)j * BD + base);
    bw1[j].v = *(const f16x8*)(Wx + (size_t)j * BD + base + 512);
  }

  for (int tb = 0; tb < T_STEPS; tb += 8) {
    #pragma unroll
    for (int j = 0; j < 8; ++j) {
      const int t = tb + j;
      U8 w0 = bw0[j], w1 = bw1[j];
      int tn = t + 8; if (tn > T_STEPS - 1) tn = T_STEPS - 1;
      bw0[j].v = *(const f16x8*)(Wx + (size_t)tn * BD + base);
      bw1[j].v = *(const f16x8*)(Wx + (size_t)tn * BD + base + 512);
      #pragma unroll
      for (int i = 0; i < 8; ++i) {
        h[i]   += (float)w0.v[i];
        h[i+8] += (float)w1.v[i];
      }
      float s0 = 0.f, s1 = 0.f, s2 = 0.f, s3 = 0.f;
      #pragma unroll
      for (int i = 0; i < 4; ++i) {
        s0 = fmaf(h[i],    h[i],    s0);
        s1 = fmaf(h[i+4],  h[i+4],  s1);
        s2 = fmaf(h[i+8],  h[i+8],  s2);
        s3 = fmaf(h[i+12], h[i+12], s3);
      }
      float s = wave_allsum((s0 + s1) + (s2 + s3));
      const float r = rsqrtf(s * (1.0f / DIMN) + 1e-6f);
      #pragma unroll
      for (int i = 0; i < 16; ++i) h[i] *= r;
      if (t < T_STEPS - 1) {
        U8 g0, g1;
        #pragma unroll
        for (int i = 0; i < 4; ++i) {
          g0.p[i] = pkrtz(h[2*i],   h[2*i+1]);
          g1.p[i] = pkrtz(h[2*i+8], h[2*i+9]);
        }
        *(f16x8*)(G0 + (size_t)(t+1) * BD + base) = g0.v;
        *(f16x8*)(G0 + (size_t)(t+1) * BD + base + 512) = g1.v;
      }
    }
  }
}

// ---------- pass-1 scan: h_{t+1} = rmsnorm(h_t + w_t + c_t/64), stores G1[t] = h_{t+1} ----------
__global__ __launch_bounds__(64) void scan1_wave(
    const f16* __restrict__ Wx, const f16* __restrict__ C,   // C pre-scaled by 64*beta
    const float* __restrict__ h0,
    f16* __restrict__ G1) {
  const int b = blockIdx.x;
  const int l = threadIdx.x;
  const size_t base = (size_t)b * DIMN + (size_t)l * 8;
  const f16x2 inv64 = { (f16)0.015625f, (f16)0.015625f };

  float h[16];
  {
    float4 a0 = *(const float4*)(h0 + base);
    float4 a1 = *(const float4*)(h0 + base + 4);
    float4 a2 = *(const float4*)(h0 + base + 512);
    float4 a3 = *(const float4*)(h0 + base + 516);
    h[0]=a0.x; h[1]=a0.y; h[2]=a0.z; h[3]=a0.w;
    h[4]=a1.x; h[5]=a1.y; h[6]=a1.z; h[7]=a1.w;
    h[8]=a2.x; h[9]=a2.y; h[10]=a2.z; h[11]=a2.w;
    h[12]=a3.x; h[13]=a3.y; h[14]=a3.z; h[15]=a3.w;
  }

  U8 bw0[8], bw1[8], bc0[8], bc1[8];
  #pragma unroll
  for (int j = 0; j < 8; ++j) {
    bw0[j].v = *(const f16x8*)(Wx + (size_t)j * BD + base);
    bw1[j].v = *(const f16x8*)(Wx + (size_t)j * BD + base + 512);
    bc0[j].v = *(const f16x8*)(C  + (size_t)j * BD + base);
    bc1[j].v = *(const f16x8*)(C  + (size_t)j * BD + base + 512);
  }

  for (int tb = 0; tb < T_STEPS; tb += 8) {
    #pragma unroll
    for (int j = 0; j < 8; ++j) {
      const int t = tb + j;
      U8 w0 = bw0[j], w1 = bw1[j], c0 = bc0[j], c1 = bc1[j];
      int tn = t + 8; if (tn > T_STEPS - 1) tn = T_STEPS - 1;
      bw0[j].v = *(const f16x8*)(Wx + (size_t)tn * BD + base);
      bw1[j].v = *(const f16x8*)(Wx + (size_t)tn * BD + base + 512);
      bc0[j].v = *(const f16x8*)(C  + (size_t)tn * BD + base);
      bc1[j].v = *(const f16x8*)(C  + (size_t)tn * BD + base + 512);
      U8 u0, u1;
      #pragma unroll
      for (int k = 0; k < 4; ++k) {
        u0.p[k] = c0.p[k] * inv64 + w0.p[k];   // v_pk_fma_f16
        u1.p[k] = c1.p[k] * inv64 + w1.p[k];
      }
      #pragma unroll
      for (int i = 0; i < 8; ++i) {
        h[i]   += (float)u0.v[i];
        h[i+8] += (float)u1.v[i];
      }
      float s0 = 0.f, s1 = 0.f, s2 = 0.f, s3 = 0.f;
      #pragma unroll
      for (int i = 0; i < 4; ++i) {
        s0 = fmaf(h[i],    h[i],    s0);
        s1 = fmaf(h[i+4],  h[i+4],  s1);
        s2 = fmaf(h[i+8],  h[i+8],  s2);
        s3 = fmaf(h[i+12], h[i+12], s3);
      }
      float s = wave_allsum((s0 + s1) + (s2 + s3));
      const float r = rsqrtf(s * (1.0f / DIMN) + 1e-6f);
      #pragma unroll
      for (int i = 0; i < 16; ++i) h[i] *= r;
      U8 g0, g1;
      #pragma unroll
      for (int i = 0; i < 4; ++i) {
        g0.p[i] = pkrtz(h[2*i],   h[2*i+1]);
        g1.p[i] = pkrtz(h[2*i+8], h[2*i+9]);
      }
      *(f16x8*)(G1 + (size_t)t * BD + base) = g0.v;
      *(f16x8*)(G1 + (size_t)t * BD + base + 512) = g1.v;
    }
  }
}

// ---------- expand: outs[t] = g*g*sigmoid(g), hout[t+1] = g; hout[0] = h0 ----------
__global__ __launch_bounds__(256) void expand_kernel(
    const f16* __restrict__ G1, const float* __restrict__ h0,
    float* __restrict__ outs, float* __restrict__ hout) {
  const long long total8 = (long long)T_STEPS * BD / 8;
  const long long idx = (long long)blockIdx.x * 256 + threadIdx.x;
  if (idx < total8) {
    const size_t e = (size_t)idx * 8;
    f16x8 g = *(const f16x8*)(G1 + e);
    float v[8], o[8];
    #pragma unroll
    for (int i = 0; i < 8; ++i) v[i] = (float)g[i];
    #pragma unroll
    for (int i = 0; i < 8; ++i) o[i] = v[i] * v[i] / (1.0f + expf(-v[i]));
    *(float4*)(hout + BD + e)     = make_float4(v[0], v[1], v[2], v[3]);
    *(float4*)(hout + BD + e + 4) = make_float4(v[4], v[5], v[6], v[7]);
    *(float4*)(outs + e)     = make_float4(o[0], o[1], o[2], o[3]);
    *(float4*)(outs + e + 4) = make_float4(o[4], o[5], o[6], o[7]);
  } else {
    const size_t j = (size_t)(idx - total8) * 8;
    if (j < (size_t)BD) {
      float4 a0 = *(const float4*)(h0 + j);
      float4 a1 = *(const float4*)(h0 + j + 4);
      *(float4*)(hout + j)     = a0;
      *(float4*)(hout + j + 4) = a1;
    }
  }
}

extern "C" void kernel_launch(void* const* d_in, const int* in_sizes, int n_in,
                              void* d_out, int out_size, void* d_ws, size_t ws_size,
                              hipStream_t stream) {
  const float* x    = (const float*)d_in[0];
  const float* h0   = (const float*)d_in[1];
  const float* W    = (const float*)d_in[2];
  const float* Wh   = (const float*)d_in[3];
  const float* bias = (const float*)d_in[4];
  const float* la   = (const float*)d_in[5];
  const float* lb   = (const float*)d_in[6];

  char* ws = (char*)d_ws;
  f16* XH   = (f16*)(ws);
  f16* W16  = (f16*)(ws + 33554432ull);
  f16* WH16 = (f16*)(ws + 35651584ull);
  f16* WX16 = (f16*)(ws + 37748736ull);
  f16* G0   = (f16*)(ws + 71303168ull);
  f16* C16  = (f16*)(ws + 104857600ull);
  f16* G1   = XH;                               // alias: XH dead after GEMM0

  float* outs = (float*)d_out;
  float* hout = outs + (size_t)T_STEPS * BD;

  cvt_f32_f16<<<dim3((MROWS * DIMN / 8) / 256), 256, 0, stream>>>(x, XH, MROWS * DIMN / 8);
  cvt_f32_f16<<<dim3((DIMN * DIMN / 8) / 256), 256, 0, stream>>>(W, W16, DIMN * DIMN / 8);
  cvt_f32_f16<<<dim3((DIMN * DIMN / 8) / 256), 256, 0, stream>>>(Wh, WH16, DIMN * DIMN / 8);

  // WX16 = alpha * (x @ W^T + b)
  gemm_bt_f16<<<dim3(MROWS / 128, DIMN / 128), 256, 0, stream>>>(XH, W16, bias, WX16, la, lb, 0);

  // pass-0 scan
  scan0_wave<<<dim3(BATCH), 64, 0, stream>>>(WX16, h0, G0);

  // C16 = 64*beta * (G0 @ Wh^T)
  gemm_bt_f16<<<dim3(MROWS / 128, DIMN / 128), 256, 0, stream>>>(G0, WH16, nullptr, C16, la, lb, 1);

  // pass-1 scan
  scan1_wave<<<dim3(BATCH), 64, 0, stream>>>(WX16, C16, h0, G1);

  // expand to fp32 outputs
  const int total8 = T_STEPS * BD / 8;
  expand_kernel<<<dim3(total8 / 256 + 16), 256, 0, stream>>>(G1, h0, outs, hout);
}